// Round 4
// baseline (204.839 us; speedup 1.0000x reference)
//
#include <hip/hip_runtime.h>

// MSDeformAttn: B=2, LQ=LV=11109, D=256, NH=8, HD=32, NL=3, NP=4
// shapes: (92,92),(46,46),(23,23); starts: 0, 8464, 10580
#define LQn   11109
#define MTOT  22218   // B * LQ

typedef __attribute__((ext_vector_type(8))) short short8;
typedef __attribute__((ext_vector_type(4))) float f32x4;

__device__ __forceinline__ unsigned short f2bf(float f) {
  union { float f; unsigned int u; } v; v.f = f;
  unsigned int r = v.u + 0x7fffu + ((v.u >> 16) & 1u);  // RNE
  return (unsigned short)(r >> 16);
}

// async global->LDS, 16B per lane; LDS dest = wave-uniform base + lane*16
__device__ __forceinline__ void g2l16(const void* g, void* l) {
  __builtin_amdgcn_global_load_lds(
      (const __attribute__((address_space(1))) unsigned int*)g,
      (__attribute__((address_space(3))) unsigned int*)l, 16, 0, 0);
}

// ---------------- cast query+value fp32 -> bf16 (8 elems/thread) ----------------
__global__ __launch_bounds__(256) void cast_both(
    const float* __restrict__ q, const float* __restrict__ v,
    unsigned short* __restrict__ qb, unsigned short* __restrict__ vb) {
  const int n8 = MTOT * 256 / 8;   // 710976
  int i = blockIdx.x * 256 + threadIdx.x;
  const float* src; unsigned short* dst; int j;
  if (i < n8) { src = q; dst = qb; j = i; }
  else        { src = v; dst = vb; j = i - n8; }
  if (j >= n8) return;
  float4 a = ((const float4*)src)[j * 2];
  float4 b = ((const float4*)src)[j * 2 + 1];
  ushort4 lo, hi;
  lo.x = f2bf(a.x); lo.y = f2bf(a.y); lo.z = f2bf(a.z); lo.w = f2bf(a.w);
  hi.x = f2bf(b.x); hi.y = f2bf(b.y); hi.z = f2bf(b.z); hi.w = f2bf(b.w);
  ((ushort4*)dst)[j * 2] = lo;
  ((ushort4*)dst)[j * 2 + 1] = hi;
}

// ---------------- weight prep: transpose to (N x K) bf16, concat+pad biases ----------------
// Wcat padded to 384 rows (rows 288..383 zero) so N=288 tiles as 3x128.
__global__ __launch_bounds__(256) void prep_weights(
    const float* __restrict__ Wval, const float* __restrict__ Woff,
    const float* __restrict__ Wattn, const float* __restrict__ Wout,
    const float* __restrict__ boff, const float* __restrict__ battn,
    unsigned short* __restrict__ Wval_t, unsigned short* __restrict__ Wcat_t,
    unsigned short* __restrict__ Wout_t, float* __restrict__ bcat) {
  int i = blockIdx.x * 256 + threadIdx.x;   // grid = 384 blocks -> i < 98304
  int n = i >> 8, k = i & 255;
  if (n < 256) {
    Wval_t[i] = f2bf(Wval[k * 256 + n]);
    Wout_t[i] = f2bf(Wout[k * 256 + n]);
  }
  float src = (n < 192) ? Woff[k * 192 + n] : (n < 288 ? Wattn[k * 96 + (n - 192)] : 0.f);
  Wcat_t[i] = f2bf(src);
  if (i < 384) bcat[i] = (i < 192) ? boff[i] : (i < 288 ? battn[i - 192] : 0.f);
}

// ---------------- 128x128 MFMA GEMM main loop (m97 structure) ----------------
// block = 256 (4 waves 2x2, each wave 64x64 = 4x4 frags of 16x16x32).
// A: (M,256) bf16 row-major; Bt: (Nrows,256) bf16 N-major. K=256 -> 8 steps of 32.
// LDS: unpadded [128][32] bf16 (global_load_lds order), 8KB each.
__device__ __forceinline__ void gemm128_loop(
    const unsigned short* __restrict__ A, int Arow0,
    const unsigned short* __restrict__ Bt, int Brow0,
    unsigned short* As, unsigned short* Bs, f32x4 (&acc)[4][4]) {
  const int t = threadIdx.x;
  const int w = t >> 6, lane = t & 63;
  const int rowl = lane >> 2;            // 0..15
  const int kby = (lane & 3) * 16;       // byte offset within 64B row
  const int quad = lane >> 4, l16 = lane & 15;
  const int wm = w >> 1, wn = w & 1;

#pragma unroll 1
  for (int kb = 0; kb < 8; kb++) {
    if (kb) __syncthreads();             // all waves done reading previous tile
#pragma unroll
    for (int i16 = 0; i16 < 2; i16++) {
      int r = w * 32 + i16 * 16 + rowl;
      int ga = Arow0 + r; ga = (ga < MTOT) ? ga : (MTOT - 1);
      g2l16((const char*)A + (size_t)ga * 512 + kb * 64 + kby,
            (char*)As + w * 2048 + i16 * 1024);
      g2l16((const char*)Bt + (size_t)(Brow0 + r) * 512 + kb * 64 + kby,
            (char*)Bs + w * 2048 + i16 * 1024);
    }
    __syncthreads();                     // drains vmcnt: LDS tiles ready
    short8 af[4], bfr[4];
#pragma unroll
    for (int i = 0; i < 4; i++)
      af[i] = *(const short8*)((const char*)As + (wm * 64 + i * 16 + l16) * 64 + quad * 16);
#pragma unroll
    for (int j = 0; j < 4; j++)
      bfr[j] = *(const short8*)((const char*)Bs + (wn * 64 + j * 16 + l16) * 64 + quad * 16);
#pragma unroll
    for (int i = 0; i < 4; i++)
#pragma unroll
      for (int j = 0; j < 4; j++)
        acc[i][j] = __builtin_amdgcn_mfma_f32_16x16x32_bf16(af[i], bfr[j], acc[i][j], 0, 0, 0);
  }
}

// grid (174, 5): bn<2 -> value proj (N=256, bf16 head-major out)
//                bn>=2 -> logits proj (N=288 of padded 384, fp32 out)
__global__ __launch_bounds__(256) void gemm128_12(
    const unsigned short* __restrict__ Av, const unsigned short* __restrict__ Aq,
    const unsigned short* __restrict__ Bv, const unsigned short* __restrict__ Bc,
    const float* __restrict__ bval, const float* __restrict__ bcat,
    unsigned short* __restrict__ value16, float* __restrict__ logits) {
  __shared__ unsigned short As[128 * 32];
  __shared__ unsigned short Bs[128 * 32];
  const int bm = blockIdx.x;
  const int bn = blockIdx.y;
  const bool is2 = bn >= 2;
  const int bnl = is2 ? bn - 2 : bn;

  f32x4 acc[4][4];
  for (int i = 0; i < 4; i++)
    for (int j = 0; j < 4; j++) acc[i][j] = (f32x4){0.f, 0.f, 0.f, 0.f};

  gemm128_loop(is2 ? Aq : Av, bm * 128, is2 ? Bc : Bv, bnl * 128, As, Bs, acc);

  const int t = threadIdx.x, lane = t & 63;
  const int quad = lane >> 4, l16 = lane & 15;
  const int wm = t >> 7, wn = (t >> 6) & 1;

  if (!is2) {
#pragma unroll
    for (int j = 0; j < 4; j++) {
      const int col = bnl * 128 + wn * 64 + j * 16 + l16;   // < 256
      const float bs = bval[col];
      const int hbase = col >> 5, cch = col & 31;
#pragma unroll
      for (int i = 0; i < 4; i++) {
        const int row0 = bm * 128 + wm * 64 + i * 16 + quad * 4;
#pragma unroll
        for (int r = 0; r < 4; r++) {
          const int rg = row0 + r;
          if (rg >= MTOT) continue;
          const int b = rg >= LQn ? 1 : 0;
          const int p = rg - b * LQn;
          value16[((size_t)(b * 8 + hbase) * LQn + p) * 32 + cch] = f2bf(acc[i][j][r] + bs);
        }
      }
    }
  } else {
#pragma unroll
    for (int j = 0; j < 4; j++) {
      const int col = bnl * 128 + wn * 64 + j * 16 + l16;
      if (col >= 288) continue;
      const float bs = bcat[col];
#pragma unroll
      for (int i = 0; i < 4; i++) {
        const int row0 = bm * 128 + wm * 64 + i * 16 + quad * 4;
#pragma unroll
        for (int r = 0; r < 4; r++) {
          const int rg = row0 + r;
          if (rg < MTOT) logits[(size_t)rg * 288 + col] = acc[i][j][r] + bs;
        }
      }
    }
  }
}

// out proj: A = sampled bf16, N=256, fp32 out. grid (174, 2)
__global__ __launch_bounds__(256) void gemm128_out(
    const unsigned short* __restrict__ A, const unsigned short* __restrict__ Bt,
    const float* __restrict__ bias, float* __restrict__ C) {
  __shared__ unsigned short As[128 * 32];
  __shared__ unsigned short Bs[128 * 32];
  const int bm = blockIdx.x, bn = blockIdx.y;

  f32x4 acc[4][4];
  for (int i = 0; i < 4; i++)
    for (int j = 0; j < 4; j++) acc[i][j] = (f32x4){0.f, 0.f, 0.f, 0.f};

  gemm128_loop(A, bm * 128, Bt, bn * 128, As, Bs, acc);

  const int t = threadIdx.x, lane = t & 63;
  const int quad = lane >> 4, l16 = lane & 15;
  const int wm = t >> 7, wn = (t >> 6) & 1;
#pragma unroll
  for (int j = 0; j < 4; j++) {
    const int col = bn * 128 + wn * 64 + j * 16 + l16;
    const float bs = bias[col];
#pragma unroll
    for (int i = 0; i < 4; i++) {
      const int row0 = bm * 128 + wm * 64 + i * 16 + quad * 4;
#pragma unroll
      for (int r = 0; r < 4; r++) {
        const int rg = row0 + r;
        if (rg < MTOT) C[(size_t)rg * 256 + col] = acc[i][j][r] + bs;
      }
    }
  }
}

// ---------------- sampling + softmax + weighted sum, v3 (unchanged) ----------------
__global__ __launch_bounds__(256) void msda_sample3(
    const unsigned short* __restrict__ value16,  // [b][h][pix][32] bf16
    const float* __restrict__ logits,            // (M,288)
    const float* __restrict__ refp,              // (M,3,2) (y,x)
    unsigned short* __restrict__ sampled) {      // (M,256) bf16
  __shared__ float lg[4][288];
  __shared__ float rfs[4][6];
  __shared__ float hmx[4][8], hrd[4][8];
  __shared__ float tw[4][96][4];
  __shared__ unsigned int ti[4][96][4];   // pix*64 byte offsets

  const int t = threadIdx.x;
  const int ql = t >> 6;
  const int lane = t & 63;
  const int bq = blockIdx.x * 4 + ql;
  const bool qv = bq < MTOT;

  if (qv) {
    for (int i = lane; i < 288; i += 64) lg[ql][i] = logits[(size_t)bq * 288 + i];
    if (lane < 6) rfs[ql][lane] = refp[(size_t)bq * 6 + lane];
  }
  __syncthreads();

  if (qv && lane < 8) {
    float mx = -1e30f;
#pragma unroll
    for (int i = 0; i < 12; i++) mx = fmaxf(mx, lg[ql][192 + lane * 12 + i]);
    float den = 0.f;
#pragma unroll
    for (int i = 0; i < 12; i++) den += __expf(lg[ql][192 + lane * 12 + i] - mx);
    hmx[ql][lane] = mx;
    hrd[ql][lane] = 1.0f / den;
  }
  __syncthreads();

  if (qv) {
    const int Hs[3] = {92, 46, 23};
    const int Ss[3] = {0, 8464, 10580};
#pragma unroll
    for (int rnd = 0; rnd < 2; rnd++) {
      const int s = lane + rnd * 64;
      if (s < 96) {
        const int h = s / 12;
        const int pl = s - h * 12;
        const int l = pl >> 2;
        const int H = Hs[l], W = Hs[l], S = Ss[l];
        const float aw = __expf(lg[ql][192 + s] - hmx[ql][h]) * hrd[ql][h];
        const float offy = lg[ql][2 * s], offx = lg[ql][2 * s + 1];
        const float x = rfs[ql][l * 2 + 1] * W + offx - 0.5f;
        const float y = rfs[ql][l * 2 + 0] * H + offy - 0.5f;
        const float xf = floorf(x), yf = floorf(y);
        const int x0 = (int)xf, y0 = (int)yf;
        const float lx = x - xf, ly = y - yf;
        const bool xv0 = (x0 >= 0) & (x0 < W), xv1 = (x0 + 1 >= 0) & (x0 + 1 < W);
        const bool yv0 = (y0 >= 0) & (y0 < H), yv1 = (y0 + 1 >= 0) & (y0 + 1 < H);
        const int xc0 = min(max(x0, 0), W - 1), xc1 = min(max(x0 + 1, 0), W - 1);
        const int yc0 = min(max(y0, 0), H - 1), yc1 = min(max(y0 + 1, 0), H - 1);
        ti[ql][s][0] = (unsigned)(S + yc0 * W + xc0) << 6;
        ti[ql][s][1] = (unsigned)(S + yc0 * W + xc1) << 6;
        ti[ql][s][2] = (unsigned)(S + yc1 * W + xc0) << 6;
        ti[ql][s][3] = (unsigned)(S + yc1 * W + xc1) << 6;
        tw[ql][s][0] = (yv0 & xv0) ? aw * (1.f - ly) * (1.f - lx) : 0.f;
        tw[ql][s][1] = (yv0 & xv1) ? aw * (1.f - ly) * lx : 0.f;
        tw[ql][s][2] = (yv1 & xv0) ? aw * ly * (1.f - lx) : 0.f;
        tw[ql][s][3] = (yv1 & xv1) ? aw * ly * lx : 0.f;
      }
    }
  }
  __syncthreads();

  if (qv) {
    const int h = lane >> 3, cg = lane & 7;
    const unsigned laneoff = (unsigned)h * (LQn * 64u) + (unsigned)cg * 8u;
    const char* __restrict__ vb =
        (const char*)(value16 + (size_t)(bq / LQn) * (8u * LQn * 32u));
    float a0 = 0.f, a1 = 0.f, a2 = 0.f, a3 = 0.f;
#pragma unroll
    for (int p = 0; p < 12; p++) {
      const int s = h * 12 + p;
      const f32x4 wv = *(const f32x4*)(&tw[ql][s][0]);
      const uint4 iv = *(const uint4*)(&ti[ql][s][0]);
#pragma unroll
      for (int k = 0; k < 4; k++) {
        const unsigned tib = (k == 0) ? iv.x : (k == 1) ? iv.y : (k == 2) ? iv.z : iv.w;
        const float w = wv[k];
        const uint2 u = *(const uint2*)(vb + (laneoff + tib));
        a0 += w * __uint_as_float(u.x << 16);
        a1 += w * __uint_as_float(u.x & 0xffff0000u);
        a2 += w * __uint_as_float(u.y << 16);
        a3 += w * __uint_as_float(u.y & 0xffff0000u);
      }
    }
    ushort4 o;
    o.x = f2bf(a0); o.y = f2bf(a1); o.z = f2bf(a2); o.w = f2bf(a3);
    *(ushort4*)(sampled + (size_t)bq * 256 + h * 32 + cg * 4) = o;
  }
}

// ---------------- host launch ----------------
extern "C" void kernel_launch(void* const* d_in, const int* in_sizes, int n_in,
                              void* d_out, int out_size, void* d_ws, size_t ws_size,
                              hipStream_t stream) {
  const float* query      = (const float*)d_in[0];
  const float* refp       = (const float*)d_in[1];
  const float* value_flat = (const float*)d_in[2];
  const float* W_val      = (const float*)d_in[3];
  const float* b_val      = (const float*)d_in[4];
  const float* W_off      = (const float*)d_in[5];
  const float* b_off      = (const float*)d_in[6];
  const float* W_attn     = (const float*)d_in[7];
  const float* b_attn     = (const float*)d_in[8];
  const float* W_out      = (const float*)d_in[9];
  const float* b_out      = (const float*)d_in[10];

  char* w = (char*)d_ws;
  size_t o = 0;
  auto carve = [&](size_t bytes) -> void* {
    void* p = (void*)(w + o);
    o += (bytes + 255) & ~(size_t)255;
    return p;
  };
  unsigned short* q_bf    = (unsigned short*)carve((size_t)MTOT * 256 * 2);
  unsigned short* v_bf    = (unsigned short*)carve((size_t)MTOT * 256 * 2);
  unsigned short* Wval_t  = (unsigned short*)carve(256 * 256 * 2);
  unsigned short* Wcat_t  = (unsigned short*)carve(384 * 256 * 2);
  unsigned short* Wout_t  = (unsigned short*)carve(256 * 256 * 2);
  float*          bcat    = (float*)carve(384 * 4);
  unsigned short* value16 = (unsigned short*)carve((size_t)MTOT * 256 * 2);
  float*          logits  = (float*)carve((size_t)MTOT * 288 * 4);
  unsigned short* samp_bf = (unsigned short*)carve((size_t)MTOT * 256 * 2);

  const int n8x2 = 2 * (MTOT * 256 / 8);
  cast_both<<<(n8x2 + 255) / 256, 256, 0, stream>>>(query, value_flat, q_bf, v_bf);
  prep_weights<<<384, 256, 0, stream>>>(W_val, W_off, W_attn, W_out, b_off, b_attn,
                                        Wval_t, Wcat_t, Wout_t, bcat);

  const int mg = (MTOT + 127) / 128;             // 174
  dim3 g12(mg, 5);                               // 2 value tiles + 3 logits tiles
  gemm128_12<<<g12, 256, 0, stream>>>(v_bf, q_bf, Wval_t, Wcat_t,
                                      b_val, bcat, value16, logits);

  const int sgrid = (MTOT + 3) / 4;              // 5555
  msda_sample3<<<sgrid, 256, 0, stream>>>(value16, logits, refp, samp_bf);

  dim3 g3(mg, 2);
  gemm128_out<<<g3, 256, 0, stream>>>(samp_bf, Wout_t, b_out, (float*)d_out);
}

// Round 5
// 190.732 us; speedup vs baseline: 1.0740x; 1.0740x over previous
//
#include <hip/hip_runtime.h>

// MSDeformAttn: B=2, LQ=LV=11109, D=256, NH=8, HD=32, NL=3, NP=4
// shapes: (92,92),(46,46),(23,23); starts: 0, 8464, 10580
#define LQn   11109
#define MTOT  22218   // B * LQ

typedef __attribute__((ext_vector_type(8))) short short8;
typedef __attribute__((ext_vector_type(4))) float f32x4;

__device__ __forceinline__ unsigned short f2bf(float f) {
  union { float f; unsigned int u; } v; v.f = f;
  unsigned int r = v.u + 0x7fffu + ((v.u >> 16) & 1u);  // RNE
  return (unsigned short)(r >> 16);
}

// ---------------- weight prep: transpose to (N x K) bf16, concat biases ----------------
__global__ __launch_bounds__(256) void prep_weights(
    const float* __restrict__ Wval, const float* __restrict__ Woff,
    const float* __restrict__ Wattn, const float* __restrict__ Wout,
    const float* __restrict__ boff, const float* __restrict__ battn,
    unsigned short* __restrict__ Wval_t, unsigned short* __restrict__ Wcat_t,
    unsigned short* __restrict__ Wout_t, float* __restrict__ bcat) {
  int i = blockIdx.x * 256 + threadIdx.x;   // grid = 288 blocks -> i < 73728
  int n = i >> 8, k = i & 255;              // Wt[n][k] = W[k][n]
  if (n < 256) {
    Wval_t[i] = f2bf(Wval[k * 256 + n]);
    Wout_t[i] = f2bf(Wout[k * 256 + n]);
  }
  float src = (n < 192) ? Woff[k * 192 + n] : Wattn[k * 96 + (n - 192)];
  Wcat_t[i] = f2bf(src);
  if (i < 288) bcat[i] = (i < 192) ? boff[i] : battn[i - 192];
}

// ---------------- fused GEMM1+GEMM2 (A fp32, converted in staging) ----------------
// grid = (348, 9): bn<4 -> value proj (N=256, bf16 head-major out)
//                  bn>=4 -> logits proj (N=288, fp32 out)
__global__ __launch_bounds__(256) void gemm_fused12(
    const float* __restrict__ Aval,           // (M,256) fp32
    const float* __restrict__ Aq,             // (M,256) fp32
    const unsigned short* __restrict__ Bval,  // (256,256) bf16 N-major
    const unsigned short* __restrict__ Bcat,  // (288,256) bf16 N-major
    const float* __restrict__ bval, const float* __restrict__ bcat,
    unsigned short* __restrict__ value16,     // [b][h][pix][32] bf16
    float* __restrict__ logits) {             // (M,288) fp32
  __shared__ unsigned short As[64][40];
  __shared__ unsigned short Bs[64][40];

  const int bm = blockIdx.x;
  int bn = blockIdx.y;
  const bool is2 = bn >= 4;
  if (is2) bn -= 4;
  const float* __restrict__ A = is2 ? Aq : Aval;
  const unsigned short* __restrict__ Bt = is2 ? Bcat : Bval;
  const float* __restrict__ bias = is2 ? bcat : bval;
  const int N = is2 ? 288 : 256;

  const int t = threadIdx.x;
  const int wave = t >> 6, lane = t & 63;
  const int wm = wave >> 1, wn = wave & 1;
  const int quad = lane >> 4, l16 = lane & 15;

  const int ldr = t >> 2;
  const int ldk = (t & 3) * 8;
  const int arow = bm * 64 + ldr;
  const int brow = bn * 64 + ldr;

  f32x4 acc[2][2];
  for (int i = 0; i < 2; i++)
    for (int j = 0; j < 2; j++) acc[i][j] = (f32x4){0.f, 0.f, 0.f, 0.f};

  for (int kb = 0; kb < 8; kb++) {
    const int k0 = kb * 32;
    float4 a0 = {0.f, 0.f, 0.f, 0.f}, a1 = a0;
    uint4 bv = {0u, 0u, 0u, 0u};
    if (arow < MTOT) {
      a0 = *(const float4*)(A + (size_t)arow * 256 + k0 + ldk);
      a1 = *(const float4*)(A + (size_t)arow * 256 + k0 + ldk + 4);
    }
    if (brow < N) bv = *(const uint4*)(Bt + (size_t)brow * 256 + k0 + ldk);
    ushort4 lo, hi;
    lo.x = f2bf(a0.x); lo.y = f2bf(a0.y); lo.z = f2bf(a0.z); lo.w = f2bf(a0.w);
    hi.x = f2bf(a1.x); hi.y = f2bf(a1.y); hi.z = f2bf(a1.z); hi.w = f2bf(a1.w);
    __syncthreads();
    *(ushort4*)(&As[ldr][ldk]) = lo;
    *(ushort4*)(&As[ldr][ldk + 4]) = hi;
    *(uint4*)(&Bs[ldr][ldk]) = bv;
    __syncthreads();
    short8 af[2], bfr[2];
    for (int i = 0; i < 2; i++)
      af[i] = *(const short8*)(&As[wm * 32 + i * 16 + l16][quad * 8]);
    for (int j = 0; j < 2; j++)
      bfr[j] = *(const short8*)(&Bs[wn * 32 + j * 16 + l16][quad * 8]);
    for (int i = 0; i < 2; i++)
      for (int j = 0; j < 2; j++)
        acc[i][j] = __builtin_amdgcn_mfma_f32_16x16x32_bf16(af[i], bfr[j], acc[i][j], 0, 0, 0);
  }

  for (int i = 0; i < 2; i++)
    for (int j = 0; j < 2; j++) {
      int colg = bn * 64 + wn * 32 + j * 16 + l16;
      if (colg >= N) continue;
      float bsv = bias[colg];
      int row0 = bm * 64 + wm * 32 + i * 16 + quad * 4;
      for (int r = 0; r < 4; r++) {
        int rg = row0 + r;
        if (rg >= MTOT) continue;
        float v = acc[i][j][r] + bsv;
        if (is2) {
          logits[(size_t)rg * 288 + colg] = v;
        } else {
          int b = (rg >= LQn) ? 1 : 0;
          int p = rg - b * LQn;
          value16[((size_t)(b * 8 + (colg >> 5)) * LQn + p) * 32 + (colg & 31)] = f2bf(v);
        }
      }
    }
}

// ---------------- GEMM3: A bf16, out fp32 (out proj) ----------------
__global__ __launch_bounds__(256) void gemm_a16(
    const unsigned short* __restrict__ A,   // (M,256) bf16
    const unsigned short* __restrict__ Bt,  // (256,256) bf16 N-major
    const float* __restrict__ bias,
    float* __restrict__ C) {                // (M,256) fp32
  __shared__ unsigned short As[64][40];
  __shared__ unsigned short Bs[64][40];

  const int t = threadIdx.x;
  const int bm = blockIdx.x, bn = blockIdx.y;
  const int wave = t >> 6, lane = t & 63;
  const int wm = wave >> 1, wn = wave & 1;
  const int quad = lane >> 4, l16 = lane & 15;

  const int ldr = t >> 2;
  const int ldk = (t & 3) * 8;
  const int arow = bm * 64 + ldr;
  const int brow = bn * 64 + ldr;

  f32x4 acc[2][2];
  for (int i = 0; i < 2; i++)
    for (int j = 0; j < 2; j++) acc[i][j] = (f32x4){0.f, 0.f, 0.f, 0.f};

  for (int kb = 0; kb < 8; kb++) {
    const int k0 = kb * 32;
    uint4 av = {0u, 0u, 0u, 0u}, bv = {0u, 0u, 0u, 0u};
    if (arow < MTOT) av = *(const uint4*)(A + (size_t)arow * 256 + k0 + ldk);
    bv = *(const uint4*)(Bt + (size_t)brow * 256 + k0 + ldk);
    __syncthreads();
    *(uint4*)(&As[ldr][ldk]) = av;
    *(uint4*)(&Bs[ldr][ldk]) = bv;
    __syncthreads();
    short8 af[2], bfr[2];
    for (int i = 0; i < 2; i++)
      af[i] = *(const short8*)(&As[wm * 32 + i * 16 + l16][quad * 8]);
    for (int j = 0; j < 2; j++)
      bfr[j] = *(const short8*)(&Bs[wn * 32 + j * 16 + l16][quad * 8]);
    for (int i = 0; i < 2; i++)
      for (int j = 0; j < 2; j++)
        acc[i][j] = __builtin_amdgcn_mfma_f32_16x16x32_bf16(af[i], bfr[j], acc[i][j], 0, 0, 0);
  }

  for (int i = 0; i < 2; i++)
    for (int j = 0; j < 2; j++) {
      int colg = bn * 64 + wn * 32 + j * 16 + l16;
      float bsv = bias[colg];
      int row0 = bm * 64 + wm * 32 + i * 16 + quad * 4;
      for (int r = 0; r < 4; r++) {
        int rg = row0 + r;
        if (rg < MTOT) C[(size_t)rg * 256 + colg] = acc[i][j][r] + bsv;
      }
    }
}

// ---------------- sampling + softmax + weighted sum, v4 ----------------
// 8 queries/block (2 per wave). Phase A: 64 (q,h) softmax stats from global
// logits (L2-hot). Phase B: 768 slot-tasks build premultiplied corner weights
// (tw, float4) + pixel indices (ti, ushort4) in LDS, slot = p*8+h so phase-C
// head-lanes hit consecutive LDS. Phase C: lane = (q=lane>>5, h=(lane>>2)&7,
// cg=lane&3), 8 ch/lane, uint4 16B gathers from head-major value16.
__global__ __launch_bounds__(256) void msda_sample4(
    const unsigned short* __restrict__ value16,  // [b][h][pix][32] bf16
    const float* __restrict__ logits,            // (M,288)
    const float* __restrict__ refp,              // (M,3,2) (y,x)
    unsigned short* __restrict__ sampled) {      // (M,256) bf16
  __shared__ float          tw[8][96][4];   // 12.3 KB
  __shared__ unsigned short ti[8][96][4];   // 6.1 KB
  __shared__ float hmx[8][8], hrd[8][8];
  __shared__ float rfs[8][6];

  const int t = threadIdx.x;
  const int qbase = blockIdx.x * 8;

  // refp: 48 consecutive floats
  if (t < 48) {
    int q = t / 6;
    if (qbase + q < MTOT) rfs[q][t - q * 6] = refp[(size_t)qbase * 6 + t];
  }
  // softmax stats: 64 (q,h) tasks, logits read from global (L2-hot)
  if (t >= 64 && t < 128) {
    int tt = t - 64;
    int q = tt >> 3, h = tt & 7;
    int bq = qbase + q;
    if (bq < MTOT) {
      const float* lrow = logits + (size_t)bq * 288 + 192 + h * 12;
      float mx = -1e30f;
#pragma unroll
      for (int i = 0; i < 12; i++) mx = fmaxf(mx, lrow[i]);
      float den = 0.f;
#pragma unroll
      for (int i = 0; i < 12; i++) den += __expf(lrow[i] - mx);
      hmx[q][h] = mx;
      hrd[q][h] = 1.0f / den;
    }
  }
  __syncthreads();

  // build tables: 8q x 96 slots = 768 tasks
  {
    const int Hs[3] = {92, 46, 23};
    const int Ss[3] = {0, 8464, 10580};
#pragma unroll
    for (int r = 0; r < 3; r++) {
      const int task = t + r * 256;
      const int q = task / 96, s = task - q * 96;
      const int bq = qbase + q;
      if (bq < MTOT) {
        const int h = s / 12, pl = s - h * 12;
        const int l = pl >> 2;
        const int H = Hs[l], W = Hs[l], S = Ss[l];
        const float* lrow = logits + (size_t)bq * 288;
        const float aw = __expf(lrow[192 + s] - hmx[q][h]) * hrd[q][h];
        const float offy = lrow[2 * s], offx = lrow[2 * s + 1];
        const float x = rfs[q][l * 2 + 1] * W + offx - 0.5f;
        const float y = rfs[q][l * 2 + 0] * H + offy - 0.5f;
        const float xf = floorf(x), yf = floorf(y);
        const int x0 = (int)xf, y0 = (int)yf;
        const float lx = x - xf, ly = y - yf;
        const bool xv0 = (x0 >= 0) & (x0 < W), xv1 = (x0 + 1 >= 0) & (x0 + 1 < W);
        const bool yv0 = (y0 >= 0) & (y0 < H), yv1 = (y0 + 1 >= 0) & (y0 + 1 < H);
        const int xc0 = min(max(x0, 0), W - 1), xc1 = min(max(x0 + 1, 0), W - 1);
        const int yc0 = min(max(y0, 0), H - 1), yc1 = min(max(y0 + 1, 0), H - 1);
        const int slot = pl * 8 + h;
        ti[q][slot][0] = (unsigned short)(S + yc0 * W + xc0);
        ti[q][slot][1] = (unsigned short)(S + yc0 * W + xc1);
        ti[q][slot][2] = (unsigned short)(S + yc1 * W + xc0);
        ti[q][slot][3] = (unsigned short)(S + yc1 * W + xc1);
        tw[q][slot][0] = (yv0 & xv0) ? aw * (1.f - ly) * (1.f - lx) : 0.f;
        tw[q][slot][1] = (yv0 & xv1) ? aw * (1.f - ly) * lx : 0.f;
        tw[q][slot][2] = (yv1 & xv0) ? aw * ly * (1.f - lx) : 0.f;
        tw[q][slot][3] = (yv1 & xv1) ? aw * ly * lx : 0.f;
      }
    }
  }
  __syncthreads();

  // gather + weighted sum: wave w handles queries qbase + 2w + {0,1}
  {
    const int w = t >> 6, lane = t & 63;
    const int q = w * 2 + (lane >> 5);
    const int h = (lane >> 2) & 7, cg = lane & 3;
    const int bq = qbase + q;
    const bool qv = bq < MTOT;
    const int bqc = qv ? bq : 0;
    const char* __restrict__ vb =
        (const char*)value16 + (size_t)(bqc / LQn) * ((size_t)LQn * 512);
    const unsigned laneoff = (unsigned)h * (LQn * 64u) + (unsigned)cg * 16u;

    float a0 = 0.f, a1 = 0.f, a2 = 0.f, a3 = 0.f;
    float a4 = 0.f, a5 = 0.f, a6 = 0.f, a7 = 0.f;
#pragma unroll
    for (int p = 0; p < 12; p++) {
      const int slot = p * 8 + h;
      const ushort4 tiv = *(const ushort4*)(&ti[q][slot][0]);
      const f32x4 wv = *(const f32x4*)(&tw[q][slot][0]);
#pragma unroll
      for (int k = 0; k < 4; k++) {
        const unsigned pix =
            (k == 0) ? tiv.x : (k == 1) ? tiv.y : (k == 2) ? tiv.z : tiv.w;
        const float wgt = wv[k];
        const uint4 u = *(const uint4*)(vb + ((pix << 6) + laneoff));
        a0 += wgt * __uint_as_float(u.x << 16);
        a1 += wgt * __uint_as_float(u.x & 0xffff0000u);
        a2 += wgt * __uint_as_float(u.y << 16);
        a3 += wgt * __uint_as_float(u.y & 0xffff0000u);
        a4 += wgt * __uint_as_float(u.z << 16);
        a5 += wgt * __uint_as_float(u.z & 0xffff0000u);
        a6 += wgt * __uint_as_float(u.w << 16);
        a7 += wgt * __uint_as_float(u.w & 0xffff0000u);
      }
    }
    if (qv) {
      uint4 o;
      o.x = (unsigned)f2bf(a0) | ((unsigned)f2bf(a1) << 16);
      o.y = (unsigned)f2bf(a2) | ((unsigned)f2bf(a3) << 16);
      o.z = (unsigned)f2bf(a4) | ((unsigned)f2bf(a5) << 16);
      o.w = (unsigned)f2bf(a6) | ((unsigned)f2bf(a7) << 16);
      *(uint4*)(sampled + (size_t)bq * 256 + h * 32 + cg * 8) = o;
    }
  }
}

// ---------------- host launch ----------------
extern "C" void kernel_launch(void* const* d_in, const int* in_sizes, int n_in,
                              void* d_out, int out_size, void* d_ws, size_t ws_size,
                              hipStream_t stream) {
  const float* query      = (const float*)d_in[0];
  const float* refp       = (const float*)d_in[1];
  const float* value_flat = (const float*)d_in[2];
  const float* W_val      = (const float*)d_in[3];
  const float* b_val      = (const float*)d_in[4];
  const float* W_off      = (const float*)d_in[5];
  const float* b_off      = (const float*)d_in[6];
  const float* W_attn     = (const float*)d_in[7];
  const float* b_attn     = (const float*)d_in[8];
  const float* W_out      = (const float*)d_in[9];
  const float* b_out      = (const float*)d_in[10];

  char* w = (char*)d_ws;
  size_t o = 0;
  auto carve = [&](size_t bytes) -> void* {
    void* p = (void*)(w + o);
    o += (bytes + 255) & ~(size_t)255;
    return p;
  };
  unsigned short* Wval_t  = (unsigned short*)carve(256 * 256 * 2);
  unsigned short* Wcat_t  = (unsigned short*)carve(288 * 256 * 2);
  unsigned short* Wout_t  = (unsigned short*)carve(256 * 256 * 2);
  float*          bcat    = (float*)carve(288 * 4);
  unsigned short* value16 = (unsigned short*)carve((size_t)MTOT * 256 * 2);
  float*          logits  = (float*)carve((size_t)MTOT * 288 * 4);
  unsigned short* samp_bf = (unsigned short*)carve((size_t)MTOT * 256 * 2);

  prep_weights<<<288, 256, 0, stream>>>(W_val, W_off, W_attn, W_out, b_off, b_attn,
                                        Wval_t, Wcat_t, Wout_t, bcat);

  const int mg = (MTOT + 63) / 64;               // 348
  dim3 g12(mg, 9);                               // 4 value-proj tiles + 5 logits tiles
  gemm_fused12<<<g12, 256, 0, stream>>>(value_flat, query, Wval_t, Wcat_t,
                                        b_val, bcat, value16, logits);

  const int sgrid = (MTOT + 7) / 8;              // 2778
  msda_sample4<<<sgrid, 256, 0, stream>>>(value16, logits, refp, samp_bf);

  dim3 g3(mg, 4);
  gemm_a16<<<g3, 256, 0, stream>>>(samp_bf, Wout_t, b_out, (float*)d_out);
}